// Round 1
// baseline (219.907 us; speedup 1.0000x reference)
//
#include <hip/hip_runtime.h>
#include <math.h>

#define EPS 1e-5f

// Shapes: B=64, C=96, H=W=56, HW=3136 (=784 float4)
// Plane LDS layout: 60 rows x 64 floats (stride 64), interior at [y+2][x+2]

// ---------------- K1: global average pool: x (B,C,56,56) -> pooled (B*C) ----
__global__ __launch_bounds__(256) void pool_kernel(const float* __restrict__ x,
                                                   float* __restrict__ pooled) {
    const int bc = blockIdx.x;
    const float4* xp4 = (const float4*)(x + (size_t)bc * 3136);
    const int tid = threadIdx.x;
    float s = 0.f;
    for (int i = tid; i < 784; i += 256) {
        float4 v = xp4[i];
        s += (v.x + v.y) + (v.z + v.w);
    }
    // wave(64) reduce
    for (int off = 32; off > 0; off >>= 1)
        s += __shfl_down(s, off, 64);
    __shared__ float wsum[4];
    if ((tid & 63) == 0) wsum[tid >> 6] = s;
    __syncthreads();
    if (tid == 0) {
        float t = (wsum[0] + wsum[1]) + (wsum[2] + wsum[3]);
        pooled[bc] = t * (1.f / 3136.f);
    }
}

// ---------------- K2: kernel predictor MLP -> sel[b] in {0,1} ---------------
// sel=1 means take the 3x3 branch (kwts[:,0] > kwts[:,1]; softmax is monotone)
__global__ __launch_bounds__(64) void sel_kernel(
    const float* __restrict__ pooled,
    const float* __restrict__ kw1, const float* __restrict__ kg1,
    const float* __restrict__ kb1, const float* __restrict__ km1,
    const float* __restrict__ kv1,
    const float* __restrict__ kw2, const float* __restrict__ kg2,
    const float* __restrict__ kb2, const float* __restrict__ km2,
    const float* __restrict__ kv2,
    int* __restrict__ sel) {
    const int b = threadIdx.x;  // 64 threads, one per sample
    const float* p = pooled + b * 96;
    double h1[4];
#pragma unroll
    for (int j = 0; j < 4; ++j) {
        double acc = 0.0;
        for (int c = 0; c < 96; ++c)
            acc += (double)p[c] * (double)kw1[j * 96 + c];
        double s = (double)kg1[j] / sqrt((double)kv1[j] + 1e-5);
        double h = acc * s + ((double)kb1[j] - (double)km1[j] * s);
        h1[j] = h * 0.5 * (1.0 + erf(h * 0.70710678118654752440));  // exact gelu
    }
    double h2[2];
#pragma unroll
    for (int k = 0; k < 2; ++k) {
        double acc = 0.0;
#pragma unroll
        for (int j = 0; j < 4; ++j) acc += h1[j] * (double)kw2[k * 4 + j];
        double s = (double)kg2[k] / sqrt((double)kv2[k] + 1e-5);
        h2[k] = acc * s + ((double)kb2[k] - (double)km2[k] * s);
    }
    sel[b] = (h2[0] > h2[1]) ? 1 : 0;
}

// ---------------- K3: fused depthwise conv + all BNs ------------------------
template <int K>
__device__ __forceinline__ void conv_tile(const float (&f)[8][8],
                                          const float (&wg)[K * K],
                                          float (&acc)[4][4]) {
    // 5x5: window row r = yy+ky, col = j+kx   (f[0][0] is (y0-2, x0-2))
    // 3x3: window row r = yy+ky+1, col = j+kx+1
    constexpr int off = (K == 3) ? 1 : 0;
#pragma unroll
    for (int yy = 0; yy < 4; ++yy) {
#pragma unroll
        for (int ky = 0; ky < K; ++ky) {
#pragma unroll
            for (int kx = 0; kx < K; ++kx) {
                const float w = wg[ky * K + kx];
#pragma unroll
                for (int j = 0; j < 4; ++j)
                    acc[yy][j] = fmaf(w, f[yy + ky + off][j + kx + off], acc[yy][j]);
            }
        }
    }
}

__global__ __launch_bounds__(256) void fused_conv_kernel(
    const float* __restrict__ x,
    const float* __restrict__ w3, const float* __restrict__ g3,
    const float* __restrict__ b3, const float* __restrict__ m3,
    const float* __restrict__ v3,
    const float* __restrict__ w5, const float* __restrict__ g5,
    const float* __restrict__ b5, const float* __restrict__ m5,
    const float* __restrict__ v5,
    const float* __restrict__ w1, const float* __restrict__ b1,
    const float* __restrict__ gbn, const float* __restrict__ bbn,
    const float* __restrict__ mbn, const float* __restrict__ vbn,
    const int* __restrict__ sel,
    float* __restrict__ out) {
    __shared__ float lds[60 * 64];
    const int bc = blockIdx.x;
    const int b = bc / 96;
    const int c = bc - b * 96;
    const int tid = threadIdx.x;

    // zero (halo) then stage interior
    for (int i = tid; i < 60 * 64; i += 256) lds[i] = 0.f;
    __syncthreads();
    const float4* xp4 = (const float4*)(x + (size_t)bc * 3136);
    for (int i = tid; i < 784; i += 256) {
        float4 v = xp4[i];
        const int y = i / 14;
        const int xq = i - y * 14;
        float2* dst = (float2*)&lds[(y + 2) * 64 + 2 + xq * 4];  // 8-mod-16 aligned
        dst[0] = make_float2(v.x, v.y);
        dst[1] = make_float2(v.z, v.w);
    }
    __syncthreads();

    if (tid >= 196) return;  // 14 quad-cols x 14 row-blocks
    const int rb = tid / 14;
    const int q = tid - rb * 14;
    const int x0 = q * 4, y0 = rb * 4;

    // 8x8 register window: rows y0-2..y0+5 (lds rows y0..y0+7), cols x0-2..x0+5
    float f[8][8];
#pragma unroll
    for (int r = 0; r < 8; ++r) {
        const float4* p = (const float4*)&lds[(y0 + r) * 64 + q * 4];  // 16B aligned
        float4 a = p[0], bb = p[1];
        f[r][0] = a.x;  f[r][1] = a.y;  f[r][2] = a.z;  f[r][3] = a.w;
        f[r][4] = bb.x; f[r][5] = bb.y; f[r][6] = bb.z; f[r][7] = bb.w;
    }

    const float sbn = gbn[c] * rsqrtf(vbn[c] + EPS);
    const float tbn = bbn[c] - mbn[c] * sbn;
    const float w1c = sbn * w1[c];   // folded 1x1 (goes into center tap)
    const float b1c = b1[c];

    float acc[4][4];
    if (sel[b]) {  // 3x3 branch, uniform per block
        const float sk = g3[c] * rsqrtf(v3[c] + EPS);
        const float A = sbn * sk;
        const float Cc = sbn * ((b3[c] - m3[c] * sk) + b1c) + tbn;
        float wg[9];
#pragma unroll
        for (int i = 0; i < 9; ++i) wg[i] = A * w3[c * 9 + i];
        wg[4] += w1c;
#pragma unroll
        for (int yy = 0; yy < 4; ++yy)
#pragma unroll
            for (int j = 0; j < 4; ++j) acc[yy][j] = Cc;
        conv_tile<3>(f, wg, acc);
    } else {       // 5x5 branch
        const float sk = g5[c] * rsqrtf(v5[c] + EPS);
        const float A = sbn * sk;
        const float Cc = sbn * ((b5[c] - m5[c] * sk) + b1c) + tbn;
        float wg[25];
#pragma unroll
        for (int i = 0; i < 25; ++i) wg[i] = A * w5[c * 25 + i];
        wg[12] += w1c;
#pragma unroll
        for (int yy = 0; yy < 4; ++yy)
#pragma unroll
            for (int j = 0; j < 4; ++j) acc[yy][j] = Cc;
        conv_tile<5>(f, wg, acc);
    }

    float* op = out + (size_t)bc * 3136;
#pragma unroll
    for (int yy = 0; yy < 4; ++yy) {
        float4 v = make_float4(acc[yy][0], acc[yy][1], acc[yy][2], acc[yy][3]);
        *(float4*)(op + (y0 + yy) * 56 + x0) = v;  // 16B aligned (224*y + 16q)
    }
}

extern "C" void kernel_launch(void* const* d_in, const int* in_sizes, int n_in,
                              void* d_out, int out_size, void* d_ws, size_t ws_size,
                              hipStream_t stream) {
    const float* x   = (const float*)d_in[0];
    const float* w3  = (const float*)d_in[1];
    const float* g3  = (const float*)d_in[2];
    const float* b3  = (const float*)d_in[3];
    const float* m3  = (const float*)d_in[4];
    const float* v3  = (const float*)d_in[5];
    const float* w5  = (const float*)d_in[6];
    const float* g5  = (const float*)d_in[7];
    const float* b5  = (const float*)d_in[8];
    const float* m5  = (const float*)d_in[9];
    const float* v5  = (const float*)d_in[10];
    const float* w1  = (const float*)d_in[11];
    const float* b1  = (const float*)d_in[12];
    const float* gbn = (const float*)d_in[13];
    const float* bbn = (const float*)d_in[14];
    const float* mbn = (const float*)d_in[15];
    const float* vbn = (const float*)d_in[16];
    const float* kw1 = (const float*)d_in[17];
    const float* kg1 = (const float*)d_in[18];
    const float* kb1 = (const float*)d_in[19];
    const float* km1 = (const float*)d_in[20];
    const float* kv1 = (const float*)d_in[21];
    const float* kw2 = (const float*)d_in[22];
    const float* kg2 = (const float*)d_in[23];
    const float* kb2 = (const float*)d_in[24];
    const float* km2 = (const float*)d_in[25];
    const float* kv2 = (const float*)d_in[26];
    float* out = (float*)d_out;

    float* pooled = (float*)d_ws;                       // 6144 floats
    int* sel = (int*)((char*)d_ws + 6144 * sizeof(float));  // 64 ints

    pool_kernel<<<6144, 256, 0, stream>>>(x, pooled);
    sel_kernel<<<1, 64, 0, stream>>>(pooled, kw1, kg1, kb1, km1, kv1,
                                     kw2, kg2, kb2, km2, kv2, sel);
    fused_conv_kernel<<<6144, 256, 0, stream>>>(
        x, w3, g3, b3, m3, v3, w5, g5, b5, m5, v5, w1, b1,
        gbn, bbn, mbn, vbn, sel, out);
}